// Round 1
// baseline (951.850 us; speedup 1.0000x reference)
//
#include <hip/hip_runtime.h>
#include <math.h>

// LocalRelationBlock fused kernel for MI355X (gfx950).
// B=8192, C=256, H=W=5, G=8 groups, SE_HID=64.
// One workgroup (512 thr = 8 waves) processes NB=4 samples end-to-end.

typedef short v8s __attribute__((ext_vector_type(8)));   // 8 x bf16 (bit pattern)
typedef float v4f __attribute__((ext_vector_type(4)));

#define NTHREADS 512
#define NB 4
#define CP 264        // padded channel stride in LDS rows (bf16 elems), 528B = 33*16B
#define YROWS 49      // 7x7 zero-bordered pixel grid

// ---- LDS layout (bytes) ----
#define Y_BYTES   (NB*YROWS*CP*2)             // 103488
#define GB_OFF    (Y_BYTES)                   // g1,b1,g2,b2 : 1024 f32
#define MASK_OFF  (GB_OFF + 1024*4)           // [NB][32] f32
#define POOL_OFF  (MASK_OFF + NB*32*4)        // [NB][256] f32
#define H_OFF     (POOL_OFF + NB*256*4)       // [NB][64] f32
#define GATE_OFF  (H_OFF + NB*64*4)           // [NB][256] f32
#define INVD_OFF  (GATE_OFF + NB*256*4)       // [NB] f32
#define SMEM_BYTES (INVD_OFF + 64)            // 117376 <= 160KiB

__device__ __forceinline__ unsigned short f2bf(float f){
  unsigned u = __float_as_uint(f);
  u = u + 0x7fffu + ((u >> 16) & 1u);          // RTNE
  return (unsigned short)(u >> 16);
}
__device__ __forceinline__ float gelu_f(float v){
  return 0.5f*v*(1.0f + erff(v*0.7071067811865475f));
}

// Pre-pack weights: W1 -> [cb][o][32] bf16, W2 -> [tap][cb][o][32] bf16,
// fc1_w -> [c][64] f32 (transposed), fc2_w -> [k][256] f32 (transposed).
__global__ void prep_kernel(const float* __restrict__ W1, const float* __restrict__ W2,
                            const float* __restrict__ fc1w, const float* __restrict__ fc2w,
                            unsigned short* __restrict__ w1ws, unsigned short* __restrict__ w2ws,
                            float* __restrict__ fc1t, float* __restrict__ fc2t)
{
  int t = blockIdx.x*blockDim.x + threadIdx.x;
  int stride = gridDim.x*blockDim.x;
  for (int i=t; i<8*256*32; i+=stride){
    int cb=i>>13, rem=i&8191, o=rem>>5, kk=rem&31;
    w1ws[i] = f2bf(W1[o*256 + cb*32 + kk]);
  }
  for (int i=t; i<9*8*256*32; i+=stride){
    int tap=i>>16, rem=i&65535, cb=rem>>13, rem2=rem&8191, o=rem2>>5, kk=rem2&31;
    w2ws[i] = f2bf(W2[o*2304 + (cb*32+kk)*9 + tap]);
  }
  for (int i=t; i<256*64; i+=stride){ int c=i>>6, h=i&63; fc1t[i]=fc1w[h*256+c]; }
  for (int i=t; i<64*256; i+=stride){ int k=i>>8, c=i&255; fc2t[i]=fc2w[c*64+k]; }
}

__global__ __launch_bounds__(NTHREADS, 2) void lrb_main(
    const float* __restrict__ xg, const float* __restrict__ maskg,
    const float* __restrict__ g1, const float* __restrict__ b1,
    const float* __restrict__ g2, const float* __restrict__ b2,
    const unsigned short* __restrict__ w1ws, const unsigned short* __restrict__ w2ws,
    const float* __restrict__ fc1t, const float* __restrict__ fc1b,
    const float* __restrict__ fc2t, const float* __restrict__ fc2b,
    float* __restrict__ outg, float* __restrict__ gateg)
{
  extern __shared__ char smem[];
  unsigned short* Y = (unsigned short*)smem;         // [NB][49][264] bf16 (xs rows 0..25, then y1n 7x7 grid)
  float* GB   = (float*)(smem + GB_OFF);
  float* MS   = (float*)(smem + MASK_OFF);
  float* POOL = (float*)(smem + POOL_OFF);
  float* HS   = (float*)(smem + H_OFF);
  float* GT   = (float*)(smem + GATE_OFF);
  float* INVD = (float*)(smem + INVD_OFF);

  const int tid  = threadIdx.x;
  const int lane = tid & 63;
  const int wid  = tid >> 6;     // 0..7
  const int mg   = wid >> 1;     // M-group: channels 64*mg..64*mg+63
  const int nh   = wid & 1;      // sample-half: samples {2nh, 2nh+1}
  const int col  = lane & 15;    // MFMA N (pixel) / A row within tile
  const int sg   = lane >> 4;    // K sub-block (8 contiguous k) / C row group
  const int b0   = blockIdx.x * NB;

  // ---------------- phase 1: zero Y, stage norm params + mask ----------------
  {
    int4 z4; z4.x=z4.y=z4.z=z4.w=0;
    for (int i = tid; i < Y_BYTES/16; i += NTHREADS) ((int4*)smem)[i] = z4;
    for (int i = tid; i < 256; i += NTHREADS){
      GB[i]=g1[i]; GB[256+i]=b1[i]; GB[512+i]=g2[i]; GB[768+i]=b2[i];
    }
    if (tid < NB*32){
      int nb = tid>>5, p = tid&31;
      MS[tid] = (p < 25) ? maskg[(size_t)(b0+nb)*25 + p] : 0.f;
    }
  }
  __syncthreads();
  if (tid < NB){
    float s=0.f;
    for (int p=0;p<25;++p) s += MS[tid*32+p];
    INVD[tid] = 1.f / fmaxf(s, 1e-8f);
  }
  // ---------------- phase 2: stage x -> Y rows 0..24 as bf16 [p][c] ----------
  for (int i = tid; i < NB*6400; i += NTHREADS){
    int nb  = i / 6400;
    int rem = i - nb*6400;
    int c   = rem / 25;
    int p   = rem - c*25;
    Y[(size_t)nb*(YROWS*CP) + p*CP + c] = f2bf(xg[(size_t)(b0+nb)*6400 + rem]);
  }
  __syncthreads();

  // ---------------- per-thread B-operand geometry ----------------
  int prow1[4]; int pbase2[4]; bool vc[4]; const unsigned short* yb[4];
  #pragma unroll
  for (int nt=0; nt<4; ++nt){
    int nb = 2*nh + (nt>>1);
    int p  = (nt&1)*16 + col;
    vc[nt] = (p < 25);
    int r = p/5, s_ = p - r*5;
    prow1[nt]  = vc[nt] ? p : 25;     // row 25 is a permanent zero row
    pbase2[nt] = 7*r + s_;            // 7x7 grid base (valid lanes only)
    yb[nt] = Y + (size_t)nb*(YROWS*CP) + sg*8;
  }
  const int arow_off = (mg*64 + col)*32 + sg*8;   // A-frag offset within a [256][32] panel

  // ---------------- conv1 (1x1): K = 256 ----------------
  v4f acc[4][4];
  #pragma unroll
  for (int mt=0;mt<4;++mt)
    #pragma unroll
    for (int nt=0;nt<4;++nt) acc[mt][nt] = (v4f){0.f,0.f,0.f,0.f};

  #pragma unroll
  for (int cb=0; cb<8; ++cb){
    v8s a[4], bb[4];
    #pragma unroll
    for (int mt=0;mt<4;++mt) a[mt] = *(const v8s*)(w1ws + cb*8192 + mt*512 + arow_off);
    #pragma unroll
    for (int nt=0;nt<4;++nt) bb[nt] = *(const v8s*)(yb[nt] + prow1[nt]*CP + cb*32);
    #pragma unroll
    for (int mt=0;mt<4;++mt)
      #pragma unroll
      for (int nt=0;nt<4;++nt)
        acc[mt][nt] = __builtin_amdgcn_mfma_f32_16x16x32_bf16(a[mt], bb[nt], acc[mt][nt], 0,0,0);
  }
  __syncthreads();   // all conv1 LDS reads of xs complete

  // ---------------- GN1 + GELU -> y1n into 7x7 zero-bordered grid ----------
  {
    float rs[2][2]={{0,0},{0,0}}, rq[2][2]={{0,0},{0,0}};
    #pragma unroll
    for (int mt=0;mt<4;++mt)
      #pragma unroll
      for (int nt=0;nt<4;++nt){
        float m = vc[nt] ? 1.f : 0.f;
        #pragma unroll
        for (int qi=0;qi<4;++qi){
          float x_ = acc[mt][nt][qi]*m;
          rs[mt>>1][nt>>1] += x_; rq[mt>>1][nt>>1] += x_*x_;
        }
      }
    #pragma unroll
    for (int off=1; off<64; off<<=1){
      #pragma unroll
      for (int gi=0;gi<2;++gi)
        #pragma unroll
        for (int bi=0;bi<2;++bi){
          rs[gi][bi] += __shfl_xor(rs[gi][bi], off, 64);
          rq[gi][bi] += __shfl_xor(rq[gi][bi], off, 64);
        }
    }
    float mean_[2][2], rstd_[2][2];
    #pragma unroll
    for (int gi=0;gi<2;++gi)
      #pragma unroll
      for (int bi=0;bi<2;++bi){
        float mu = rs[gi][bi]*(1.f/800.f);
        float vr = rq[gi][bi]*(1.f/800.f) - mu*mu;
        mean_[gi][bi]=mu; rstd_[gi][bi]=rsqrtf(vr+1e-5f);
      }
    #pragma unroll
    for (int nt=0;nt<4;++nt){
      if (vc[nt]){
        int nb = 2*nh+(nt>>1);
        unsigned short* dst = Y + (size_t)nb*(YROWS*CP) + (pbase2[nt]+8)*CP;  // (r+1)*7+(s+1)
        #pragma unroll
        for (int mt=0;mt<4;++mt)
          #pragma unroll
          for (int qi=0;qi<4;++qi){
            int ch = mg*64+mt*16+sg*4+qi;
            float f = (acc[mt][nt][qi]-mean_[mt>>1][nt>>1])*rstd_[mt>>1][nt>>1]*GB[ch]+GB[256+ch];
            dst[ch] = f2bf(gelu_f(f));
          }
      }
    }
  }
  // re-zero border rows dirtied by the xs staging (rows 0..7,13,14,20,21)
  {
    int4 z4; z4.x=z4.y=z4.z=z4.w=0;
    for (int i = tid; i < NB*12*32; i += NTHREADS){
      int nb  = i / (12*32);
      int rem = i - nb*(12*32);
      int rr  = rem >> 5, cc = rem & 31;
      int row = rr < 8 ? rr : (rr < 10 ? rr + 5 : rr + 10);
      *(int4*)((char*)Y + (size_t)nb*YROWS*CP*2 + (size_t)row*CP*2 + cc*16) = z4;
    }
  }
  __syncthreads();

  // ---------------- conv2 (3x3 via 9 shifted GEMM taps): K = 2304 ----------
  v4f acc2[4][4];
  #pragma unroll
  for (int mt=0;mt<4;++mt)
    #pragma unroll
    for (int nt=0;nt<4;++nt) acc2[mt][nt] = (v4f){0.f,0.f,0.f,0.f};

  #pragma unroll 1
  for (int tap=0; tap<9; ++tap){
    int dr = tap/3, ds_ = tap - dr*3;
    int off7 = dr*7 + ds_;
    const unsigned short* bp[4];
    #pragma unroll
    for (int nt=0;nt<4;++nt){
      int row = vc[nt] ? (pbase2[nt] + off7) : 0;   // row 0 = zero border
      bp[nt] = yb[nt] + row*CP;
    }
    const unsigned short* ap = w2ws + tap*65536 + arow_off;
    #pragma unroll
    for (int cb=0; cb<8; ++cb){
      v8s a[4], bb[4];
      #pragma unroll
      for (int mt=0;mt<4;++mt) a[mt] = *(const v8s*)(ap + cb*8192 + mt*512);
      #pragma unroll
      for (int nt=0;nt<4;++nt) bb[nt] = *(const v8s*)(bp[nt] + cb*32);
      #pragma unroll
      for (int mt=0;mt<4;++mt)
        #pragma unroll
        for (int nt=0;nt<4;++nt)
          acc2[mt][nt] = __builtin_amdgcn_mfma_f32_16x16x32_bf16(a[mt], bb[nt], acc2[mt][nt], 0,0,0);
    }
  }

  // ---------------- GN2 + GELU + residual + masked pooling ----------------
  {
    float rs[2][2]={{0,0},{0,0}}, rq[2][2]={{0,0},{0,0}};
    #pragma unroll
    for (int mt=0;mt<4;++mt)
      #pragma unroll
      for (int nt=0;nt<4;++nt){
        float m = vc[nt] ? 1.f : 0.f;
        #pragma unroll
        for (int qi=0;qi<4;++qi){
          float x_ = acc2[mt][nt][qi]*m;
          rs[mt>>1][nt>>1] += x_; rq[mt>>1][nt>>1] += x_*x_;
        }
      }
    #pragma unroll
    for (int off=1; off<64; off<<=1){
      #pragma unroll
      for (int gi=0;gi<2;++gi)
        #pragma unroll
        for (int bi=0;bi<2;++bi){
          rs[gi][bi] += __shfl_xor(rs[gi][bi], off, 64);
          rq[gi][bi] += __shfl_xor(rq[gi][bi], off, 64);
        }
    }
    float mean_[2][2], rstd_[2][2];
    #pragma unroll
    for (int gi=0;gi<2;++gi)
      #pragma unroll
      for (int bi=0;bi<2;++bi){
        float mu = rs[gi][bi]*(1.f/800.f);
        float vr = rq[gi][bi]*(1.f/800.f) - mu*mu;
        mean_[gi][bi]=mu; rstd_[gi][bi]=rsqrtf(vr+1e-5f);
      }
    float psum[4][2][4];
    #pragma unroll
    for (int mt=0;mt<4;++mt)
      #pragma unroll
      for (int bi=0;bi<2;++bi)
        #pragma unroll
        for (int qi=0;qi<4;++qi) psum[mt][bi][qi]=0.f;

    #pragma unroll
    for (int nt=0;nt<4;++nt){
      int bi = nt>>1; int nb = 2*nh+bi;
      int p  = (nt&1)*16+col;
      bool v = vc[nt];
      float mk = v ? MS[nb*32+p] : 0.f;
      #pragma unroll
      for (int mt=0;mt<4;++mt)
        #pragma unroll
        for (int qi=0;qi<4;++qi){
          int ch = mg*64+mt*16+sg*4+qi;
          float f = (acc2[mt][nt][qi]-mean_[mt>>1][bi])*rstd_[mt>>1][bi]*GB[512+ch]+GB[768+ch];
          f = gelu_f(f);
          if (v) f += xg[((size_t)(b0+nb)*256+ch)*25+p];   // f32 residual
          acc2[mt][nt][qi] = f;
          psum[mt][bi][qi] += f*mk;
        }
    }
    #pragma unroll
    for (int off=1; off<16; off<<=1){
      #pragma unroll
      for (int mt=0;mt<4;++mt)
        #pragma unroll
        for (int bi=0;bi<2;++bi)
          #pragma unroll
          for (int qi=0;qi<4;++qi)
            psum[mt][bi][qi] += __shfl_xor(psum[mt][bi][qi], off, 64);
    }
    if (col == 0){
      #pragma unroll
      for (int mt=0;mt<4;++mt)
        #pragma unroll
        for (int bi=0;bi<2;++bi)
          #pragma unroll
          for (int qi=0;qi<4;++qi)
            POOL[(2*nh+bi)*256 + mg*64+mt*16+sg*4+qi] = psum[mt][bi][qi];
    }
  }
  __syncthreads();

  // ---------------- SE FC1 (pooled @ fc1^T + b -> gelu) ----------------
  if (tid < 256){
    int bi = tid >> 6, hid = tid & 63;
    const float* pl = POOL + bi*256;
    float dot = 0.f;
    #pragma unroll 4
    for (int c=0;c<256;++c) dot += fc1t[c*64+hid]*pl[c];
    HS[bi*64+hid] = gelu_f(fc1b[hid] + INVD[bi]*dot);
  }
  __syncthreads();
  // ---------------- SE FC2 -> sigmoid gate (LDS + global) ----------------
  {
    int ch = tid & 255, bh = tid >> 8;
    #pragma unroll
    for (int rep=0;rep<2;++rep){
      int bi = bh + rep*2;
      const float* hp = HS + bi*64;
      float dot = 0.f;
      #pragma unroll 4
      for (int k=0;k<64;++k) dot += fc2t[k*256+ch]*hp[k];
      float gv = 1.f/(1.f+expf(-(dot + fc2b[ch])));
      GT[bi*256+ch] = gv;
      gateg[(size_t)(b0+bi)*256+ch] = gv;
    }
  }
  __syncthreads();

  // ---------------- final: out = out_pre * gate * mask ----------------
  #pragma unroll
  for (int nt=0;nt<4;++nt){
    if (!vc[nt]) continue;
    int bi = nt>>1; int nb = 2*nh+bi;
    int p  = (nt&1)*16+col;
    float mk = MS[nb*32+p];   // mask in {0,1}: mask*mask == mask
    #pragma unroll
    for (int mt=0;mt<4;++mt)
      #pragma unroll
      for (int qi=0;qi<4;++qi){
        int ch = mg*64+mt*16+sg*4+qi;
        outg[((size_t)(b0+nb)*256+ch)*25+p] = acc2[mt][nt][qi]*GT[nb*256+ch]*mk;
      }
  }
}

extern "C" void kernel_launch(void* const* d_in, const int* in_sizes, int n_in,
                              void* d_out, int out_size, void* d_ws, size_t ws_size,
                              hipStream_t stream)
{
  const float* xg   = (const float*)d_in[0];
  const float* pm   = (const float*)d_in[1];
  const float* W1   = (const float*)d_in[2];
  const float* g1   = (const float*)d_in[3];
  const float* b1   = (const float*)d_in[4];
  const float* W2   = (const float*)d_in[5];
  const float* g2   = (const float*)d_in[6];
  const float* b2   = (const float*)d_in[7];
  const float* fc1w = (const float*)d_in[8];
  const float* fc1b = (const float*)d_in[9];
  const float* fc2w = (const float*)d_in[10];
  const float* fc2b = (const float*)d_in[11];

  float* outg  = (float*)d_out;
  float* gateg = outg + (size_t)8192*256*25;

  unsigned short* w1ws = (unsigned short*)d_ws;       // 8*256*32 bf16
  unsigned short* w2ws = w1ws + 8*256*32;             // 9*8*256*32 bf16
  float* fc1t = (float*)(w2ws + 9*8*256*32);          // 256*64 f32
  float* fc2t = fc1t + 256*64;                        // 64*256 f32

  prep_kernel<<<dim3(512), dim3(256), 0, stream>>>(W1, W2, fc1w, fc2w, w1ws, w2ws, fc1t, fc2t);

  hipFuncSetAttribute(reinterpret_cast<const void*>(lrb_main),
                      hipFuncAttributeMaxDynamicSharedMemorySize, (int)SMEM_BYTES);
  lrb_main<<<dim3(2048), dim3(NTHREADS), SMEM_BYTES, stream>>>(
      xg, pm, g1, b1, g2, b2, w1ws, w2ws, fc1t, fc1b, fc2t, fc2b, outg, gateg);
}

// Round 2
// 906.438 us; speedup vs baseline: 1.0501x; 1.0501x over previous
//
#include <hip/hip_runtime.h>
#include <math.h>

// LocalRelationBlock fused kernel for MI355X (gfx950).
// B=8192, C=256, H=W=5, G=8 groups, SE_HID=64.
// R2: NB=2 samples/WG (2 WG/CU -> 4 waves/SIMD), reg-prefetched MFMA loops,
//     conflict-free vectorized LDS staging, LDS-staged coalesced output.

typedef short v8s __attribute__((ext_vector_type(8)));   // 8 x bf16 (bit pattern)
typedef float v4f __attribute__((ext_vector_type(4)));

#define NTHREADS 512
#define NB 2
#define CP 264        // padded channel stride in LDS rows (bf16 elems), 528B
#define YROWS 49      // 7x7 zero-bordered pixel grid
#define YSTRIDE (YROWS*CP)   // 12936 elems per sample

// ---- LDS layout (bytes) ----
#define Y_BYTES   (NB*YSTRIDE*2)              // 51744
#define GB_OFF    (Y_BYTES)                   // g1,b1,g2,b2 : 1024 f32
#define MASK_OFF  (GB_OFF + 1024*4)           // [NB][32] f32
#define POOL_OFF  (MASK_OFF + NB*32*4)        // [NB][256] f32
#define H_OFF     (POOL_OFF + NB*256*4)       // [NB][64] f32
#define GATE_OFF  (H_OFF + NB*64*4)           // [NB][256] f32
#define INVD_OFF  (GATE_OFF + NB*256*4)       // [NB] f32
#define SMEM_BYTES (INVD_OFF + 64)            // 60768

__device__ __forceinline__ unsigned short f2bf(float f){
  unsigned u = __float_as_uint(f);
  u = u + 0x7fffu + ((u >> 16) & 1u);          // RTNE
  return (unsigned short)(u >> 16);
}
// erf via Abramowitz-Stegun 7.1.26 (|eps| < 1.5e-7), exp2/rcp fast paths
__device__ __forceinline__ float gelu_f(float v){
  float z  = fabsf(v) * 0.70710678118654752f;
  float t  = __builtin_amdgcn_rcpf(fmaf(0.3275911f, z, 1.0f));
  float e  = __builtin_amdgcn_exp2f(-z*z*1.4426950408889634f);
  float p  = fmaf(1.061405429f, t, -1.453152027f);
  p = fmaf(p, t, 1.421413741f);
  p = fmaf(p, t, -0.284496736f);
  p = fmaf(p, t, 0.254829592f);
  float er = fmaf(-p*t, e, 1.0f);              // erf(z), z>=0
  er = __builtin_copysignf(er, v);
  return 0.5f*v*(1.0f + er);
}

// Pre-pack weights: W1 -> [cb][o][32] bf16, W2 -> [tap][cb][o][32] bf16,
// fc1_w -> [c][64] f32 (transposed), fc2_w -> [k][256] f32 (transposed).
__global__ void prep_kernel(const float* __restrict__ W1, const float* __restrict__ W2,
                            const float* __restrict__ fc1w, const float* __restrict__ fc2w,
                            unsigned short* __restrict__ w1ws, unsigned short* __restrict__ w2ws,
                            float* __restrict__ fc1t, float* __restrict__ fc2t)
{
  int t = blockIdx.x*blockDim.x + threadIdx.x;
  int stride = gridDim.x*blockDim.x;
  for (int i=t; i<8*256*32; i+=stride){
    int cb=i>>13, rem=i&8191, o=rem>>5, kk=rem&31;
    w1ws[i] = f2bf(W1[o*256 + cb*32 + kk]);
  }
  for (int i=t; i<9*8*256*32; i+=stride){
    int tap=i>>16, rem=i&65535, cb=rem>>13, rem2=rem&8191, o=rem2>>5, kk=rem2&31;
    w2ws[i] = f2bf(W2[o*2304 + (cb*32+kk)*9 + tap]);
  }
  for (int i=t; i<256*64; i+=stride){ int c=i>>6, h=i&63; fc1t[i]=fc1w[h*256+c]; }
  for (int i=t; i<64*256; i+=stride){ int k=i>>8, c=i&255; fc2t[i]=fc2w[c*64+k]; }
}

__global__ __launch_bounds__(NTHREADS, 4) void lrb_main(
    const float* __restrict__ xg, const float* __restrict__ maskg,
    const float* __restrict__ g1, const float* __restrict__ b1,
    const float* __restrict__ g2, const float* __restrict__ b2,
    const unsigned short* __restrict__ w1ws, const unsigned short* __restrict__ w2ws,
    const float* __restrict__ fc1t, const float* __restrict__ fc1b,
    const float* __restrict__ fc2t, const float* __restrict__ fc2b,
    float* __restrict__ outg, float* __restrict__ gateg)
{
  extern __shared__ char smem[];
  unsigned short* Y = (unsigned short*)smem;   // [NB][49][264] bf16; later reused as OUTF f32
  float* OUTF = (float*)smem;                  // [NB][256][25] f32 (51200B <= 51744B)
  float* GB   = (float*)(smem + GB_OFF);
  float* MS   = (float*)(smem + MASK_OFF);
  float* POOL = (float*)(smem + POOL_OFF);
  float* HS   = (float*)(smem + H_OFF);
  float* GT   = (float*)(smem + GATE_OFF);
  float* INVD = (float*)(smem + INVD_OFF);

  const int tid  = threadIdx.x;
  const int lane = tid & 63;
  const int wid  = tid >> 6;     // 0..7
  const int mg   = wid >> 1;     // M-group: channels 64*mg..64*mg+63
  const int nb   = wid & 1;      // sample within WG
  const int col  = lane & 15;    // MFMA N (pixel) / A row within tile
  const int sg   = lane >> 4;    // K sub-block (8 contiguous k)
  const int b0   = blockIdx.x * NB;

  // ---------------- phase 1: zero Y, stage norm params + mask ----------------
  {
    int4 z4; z4.x=z4.y=z4.z=z4.w=0;
    for (int i = tid; i < Y_BYTES/16; i += NTHREADS) ((int4*)smem)[i] = z4;
    if (tid < 256){
      GB[tid]=g1[tid]; GB[256+tid]=b1[tid]; GB[512+tid]=g2[tid]; GB[768+tid]=b2[tid];
    }
    if (tid >= 256 && tid < 256 + NB*32){
      int t2 = tid - 256;
      int nbb = t2>>5, p = t2&31;
      MS[t2] = (p < 25) ? maskg[(size_t)(b0+nbb)*25 + p] : 0.f;
    }
  }
  // ---------------- per-thread geometry ----------------
  int prow1[2]; int pbase_eff[2]; int vstep[2]; bool vc[2];
  #pragma unroll
  for (int nt=0; nt<2; ++nt){
    int p  = nt*16 + col;
    vc[nt] = (p < 25);
    int r = p/5, s_ = p - r*5;
    prow1[nt]     = vc[nt] ? p : 25;           // row 25 is a permanent zero row
    pbase_eff[nt] = vc[nt] ? (7*r + s_) : 0;   // 7x7 grid base (0 for invalid)
    vstep[nt]     = vc[nt] ? CP : 0;
  }
  const int arow_off = (mg*64 + col)*32 + sg*8;     // A-frag offset in [256][32] panel
  unsigned short* yb = Y + nb*YSTRIDE + sg*8;
  const unsigned short* apW1 = w1ws + arow_off;
  const unsigned short* apW2 = w2ws + arow_off;

  __syncthreads();   // zeroing complete

  if (tid < NB){
    float s=0.f;
    #pragma unroll
    for (int p=0;p<25;++p) s += MS[tid*32+p];
    INVD[tid] = __builtin_amdgcn_rcpf(fmaxf(s, 1e-8f));
  }

  // conv1 A prefetch (global, independent of LDS) -- issue before staging
  v8s A[4], An[4], Bf[2], Bn[2];
  #pragma unroll
  for (int mt=0;mt<4;++mt) A[mt] = *(const v8s*)(apW1 + mt*512);

  // ---------------- phase 2: stage x -> Y rows 0..24 as bf16 [p][c] ----------
  // thread handles (nb, pixel, channel-octet): strided global reads,
  // contiguous 16B LDS writes (conflict-free).
  for (int i = tid; i < NB*25*32; i += NTHREADS){
    int nbb = i / 800;
    int rem = i - nbb*800;
    int p   = rem >> 5;        // 0..24
    int c8  = rem & 31;        // channel octet
    const float* src = xg + ((size_t)(b0+nbb)*256 + c8*8)*25 + p;
    v8s pk;
    #pragma unroll
    for (int k=0;k<8;++k) pk[k] = (short)f2bf(src[k*25]);
    *(v8s*)(Y + nbb*YSTRIDE + p*CP + c8*8) = pk;
  }
  __syncthreads();

  // ---------------- conv1 (1x1): K = 256, depth-1 prefetch ----------------
  v4f acc[4][2];
  #pragma unroll
  for (int mt=0;mt<4;++mt){ acc[mt][0]=(v4f){0,0,0,0}; acc[mt][1]=(v4f){0,0,0,0}; }

  {
    const unsigned short* pB1[2];
    #pragma unroll
    for (int nt=0;nt<2;++nt) pB1[nt] = yb + prow1[nt]*CP;
    #pragma unroll
    for (int nt=0;nt<2;++nt) Bf[nt] = *(const v8s*)(pB1[nt]);
    #pragma unroll
    for (int cb=0; cb<8; ++cb){
      if (cb+1 < 8){
        #pragma unroll
        for (int mt=0;mt<4;++mt) An[mt] = *(const v8s*)(apW1 + (cb+1)*8192 + mt*512);
        #pragma unroll
        for (int nt=0;nt<2;++nt) Bn[nt] = *(const v8s*)(pB1[nt] + (cb+1)*32);
      }
      #pragma unroll
      for (int mt=0;mt<4;++mt)
        #pragma unroll
        for (int nt=0;nt<2;++nt)
          acc[mt][nt] = __builtin_amdgcn_mfma_f32_16x16x32_bf16(A[mt], Bf[nt], acc[mt][nt], 0,0,0);
      #pragma unroll
      for (int mt=0;mt<4;++mt) A[mt] = An[mt];
      Bf[0]=Bn[0]; Bf[1]=Bn[1];
    }
  }
  __syncthreads();   // all conv1 LDS reads of xs complete

  // ---------------- GN1 + GELU -> y1n into 7x7 zero-bordered grid ----------
  {
    float rs[2]={0,0}, rq[2]={0,0};
    #pragma unroll
    for (int mt=0;mt<4;++mt)
      #pragma unroll
      for (int nt=0;nt<2;++nt){
        float m = vc[nt] ? 1.f : 0.f;
        #pragma unroll
        for (int qi=0;qi<4;++qi){
          float x_ = acc[mt][nt][qi]*m;
          rs[mt>>1] += x_; rq[mt>>1] += x_*x_;
        }
      }
    #pragma unroll
    for (int off=1; off<64; off<<=1){
      #pragma unroll
      for (int gi=0;gi<2;++gi){
        rs[gi] += __shfl_xor(rs[gi], off, 64);
        rq[gi] += __shfl_xor(rq[gi], off, 64);
      }
    }
    float mean_[2], rstd_[2];
    #pragma unroll
    for (int gi=0;gi<2;++gi){
      float mu = rs[gi]*(1.f/800.f);
      float vr = rq[gi]*(1.f/800.f) - mu*mu;
      mean_[gi]=mu; rstd_[gi]=rsqrtf(vr+1e-5f);
    }
    #pragma unroll
    for (int nt=0;nt<2;++nt){
      if (vc[nt]){
        unsigned short* dst = Y + nb*YSTRIDE + (pbase_eff[nt]+8)*CP;  // (r+1)*7+(s+1)
        #pragma unroll
        for (int mt=0;mt<4;++mt)
          #pragma unroll
          for (int qi=0;qi<4;++qi){
            int ch = mg*64+mt*16+sg*4+qi;
            float f = (acc[mt][nt][qi]-mean_[mt>>1])*rstd_[mt>>1]*GB[ch]+GB[256+ch];
            dst[ch] = f2bf(gelu_f(f));
          }
      }
    }
  }
  // re-zero border rows dirtied by the xs staging (rows 0..7,13,14,20,21)
  {
    int4 z4; z4.x=z4.y=z4.z=z4.w=0;
    for (int i = tid; i < NB*12*32; i += NTHREADS){
      int nbb = i / (12*32);
      int rem = i - nbb*(12*32);
      int rr  = rem >> 5, cc = rem & 31;
      int row = rr < 8 ? rr : (rr < 10 ? rr + 5 : rr + 10);
      *(int4*)((char*)Y + (size_t)nbb*YSTRIDE*2 + (size_t)row*CP*2 + cc*16) = z4;
    }
  }
  // conv2 first A prefetch (global) before the barrier
  #pragma unroll
  for (int mt=0;mt<4;++mt) A[mt] = *(const v8s*)(apW2 + mt*512);
  __syncthreads();

  // ---------------- conv2 (3x3 via 9 shifted GEMM taps): K = 2304 ----------
  v4f acc2[4][2];
  #pragma unroll
  for (int mt=0;mt<4;++mt){ acc2[mt][0]=(v4f){0,0,0,0}; acc2[mt][1]=(v4f){0,0,0,0}; }

  {
    const unsigned short* pB2[2];
    #pragma unroll
    for (int nt=0;nt<2;++nt) pB2[nt] = yb + pbase_eff[nt]*CP;
    static const int OFF7[9] = {0,1,2,7,8,9,14,15,16};
    // B frags for it=0 (tap 0, cb 0)
    #pragma unroll
    for (int nt=0;nt<2;++nt) Bf[nt] = *(const v8s*)(pB2[nt] + OFF7[0]*vstep[nt]);

    #pragma unroll
    for (int it=0; it<72; ++it){
      if (it+1 < 72){
        int tap1 = (it+1) >> 3, cb1 = (it+1) & 7;
        #pragma unroll
        for (int mt=0;mt<4;++mt) An[mt] = *(const v8s*)(apW2 + (it+1)*8192 + mt*512);
        #pragma unroll
        for (int nt=0;nt<2;++nt) Bn[nt] = *(const v8s*)(pB2[nt] + OFF7[tap1]*vstep[nt] + cb1*32);
      }
      #pragma unroll
      for (int mt=0;mt<4;++mt)
        #pragma unroll
        for (int nt=0;nt<2;++nt)
          acc2[mt][nt] = __builtin_amdgcn_mfma_f32_16x16x32_bf16(A[mt], Bf[nt], acc2[mt][nt], 0,0,0);
      #pragma unroll
      for (int mt=0;mt<4;++mt) A[mt] = An[mt];
      Bf[0]=Bn[0]; Bf[1]=Bn[1];
    }
  }
  __syncthreads();   // conv2 LDS reads complete; Y becomes OUTF

  // ---------------- GN2 + GELU + residual + OUT-stage + masked pooling ------
  {
    float rs[2]={0,0}, rq[2]={0,0};
    #pragma unroll
    for (int mt=0;mt<4;++mt)
      #pragma unroll
      for (int nt=0;nt<2;++nt){
        float m = vc[nt] ? 1.f : 0.f;
        #pragma unroll
        for (int qi=0;qi<4;++qi){
          float x_ = acc2[mt][nt][qi]*m;
          rs[mt>>1] += x_; rq[mt>>1] += x_*x_;
        }
      }
    #pragma unroll
    for (int off=1; off<64; off<<=1){
      #pragma unroll
      for (int gi=0;gi<2;++gi){
        rs[gi] += __shfl_xor(rs[gi], off, 64);
        rq[gi] += __shfl_xor(rq[gi], off, 64);
      }
    }
    float mean_[2], rstd_[2];
    #pragma unroll
    for (int gi=0;gi<2;++gi){
      float mu = rs[gi]*(1.f/800.f);
      float vr = rq[gi]*(1.f/800.f) - mu*mu;
      mean_[gi]=mu; rstd_[gi]=rsqrtf(vr+1e-5f);
    }
    float psum[4][4];
    #pragma unroll
    for (int mt=0;mt<4;++mt)
      #pragma unroll
      for (int qi=0;qi<4;++qi) psum[mt][qi]=0.f;

    #pragma unroll
    for (int nt=0;nt<2;++nt){
      int p = nt*16+col;
      bool v = vc[nt];
      float mk = v ? MS[nb*32+p] : 0.f;
      #pragma unroll
      for (int mt=0;mt<4;++mt)
        #pragma unroll
        for (int qi=0;qi<4;++qi){
          int ch = mg*64+mt*16+sg*4+qi;
          float f = (acc2[mt][nt][qi]-mean_[mt>>1])*rstd_[mt>>1]*GB[512+ch]+GB[768+ch];
          f = gelu_f(f);
          if (v){
            f += xg[((size_t)(b0+nb)*256+ch)*25+p];   // f32 residual
            OUTF[nb*6400 + ch*25 + p] = f;
          }
          psum[mt][qi] += f*mk;
        }
    }
    #pragma unroll
    for (int off=1; off<16; off<<=1)
      #pragma unroll
      for (int mt=0;mt<4;++mt)
        #pragma unroll
        for (int qi=0;qi<4;++qi)
          psum[mt][qi] += __shfl_xor(psum[mt][qi], off, 64);
    if (col == 0){
      #pragma unroll
      for (int mt=0;mt<4;++mt)
        #pragma unroll
        for (int qi=0;qi<4;++qi)
          POOL[nb*256 + mg*64+mt*16+sg*4+qi] = psum[mt][qi];
    }
  }
  __syncthreads();

  // ---------------- SE FC1: 4-way split dot + shuffle combine ----------------
  {
    int nbb  = tid >> 8;          // 0..1
    int hid  = (tid >> 2) & 63;
    int part = tid & 3;
    const float* pl = POOL + nbb*256 + part*64;
    const float* wp = fc1t + part*64*64 + hid;
    float dot = 0.f;
    #pragma unroll 8
    for (int c=0;c<64;++c) dot += wp[c*64]*pl[c];
    dot += __shfl_xor(dot, 1, 64);
    dot += __shfl_xor(dot, 2, 64);
    if (part == 0)
      HS[nbb*64+hid] = gelu_f(fmaf(INVD[nbb], dot, fc1b[hid]));
  }
  __syncthreads();
  // ---------------- SE FC2 -> sigmoid gate (LDS + global) ----------------
  {
    int ch = tid & 255, nbb = tid >> 8;
    const float* hp = HS + nbb*64;
    float dot = 0.f;
    #pragma unroll 8
    for (int k=0;k<64;++k) dot += fc2t[k*256+ch]*hp[k];
    dot += fc2b[ch];
    float gv = __builtin_amdgcn_rcpf(1.0f + __builtin_amdgcn_exp2f(-dot*1.4426950408889634f));
    GT[nbb*256+ch] = gv;
    gateg[(size_t)(b0+nbb)*256+ch] = gv;
  }
  __syncthreads();

  // ---------------- final coalesced store: out = OUTF * gate * mask --------
  for (int i = tid; i < NB*1600; i += NTHREADS){
    int nbb = i / 1600;
    int r4  = i - nbb*1600;
    int e0  = r4*4;
    v4f o4 = *(const v4f*)(OUTF + nbb*6400 + e0);
    #pragma unroll
    for (int k=0;k<4;++k){
      int e = e0+k;
      int ch = e/25;
      int p  = e - ch*25;
      o4[k] = o4[k] * GT[nbb*256+ch] * MS[nbb*32+p];
    }
    *(v4f*)(outg + (size_t)(b0+nbb)*6400 + e0) = o4;
  }
}

extern "C" void kernel_launch(void* const* d_in, const int* in_sizes, int n_in,
                              void* d_out, int out_size, void* d_ws, size_t ws_size,
                              hipStream_t stream)
{
  const float* xg   = (const float*)d_in[0];
  const float* pm   = (const float*)d_in[1];
  const float* W1   = (const float*)d_in[2];
  const float* g1   = (const float*)d_in[3];
  const float* b1   = (const float*)d_in[4];
  const float* W2   = (const float*)d_in[5];
  const float* g2   = (const float*)d_in[6];
  const float* b2   = (const float*)d_in[7];
  const float* fc1w = (const float*)d_in[8];
  const float* fc1b = (const float*)d_in[9];
  const float* fc2w = (const float*)d_in[10];
  const float* fc2b = (const float*)d_in[11];

  float* outg  = (float*)d_out;
  float* gateg = outg + (size_t)8192*256*25;

  unsigned short* w1ws = (unsigned short*)d_ws;       // 8*256*32 bf16
  unsigned short* w2ws = w1ws + 8*256*32;             // 9*8*256*32 bf16
  float* fc1t = (float*)(w2ws + 9*8*256*32);          // 256*64 f32 (transposed)
  float* fc2t = fc1t + 256*64;                        // 64*256 f32 (transposed)

  prep_kernel<<<dim3(512), dim3(256), 0, stream>>>(W1, W2, fc1w, fc2w, w1ws, w2ws, fc1t, fc2t);

  hipFuncSetAttribute(reinterpret_cast<const void*>(lrb_main),
                      hipFuncAttributeMaxDynamicSharedMemorySize, (int)SMEM_BYTES);
  lrb_main<<<dim3(4096), dim3(NTHREADS), SMEM_BYTES, stream>>>(
      xg, pm, g1, b1, g2, b2, w1ws, w2ws, fc1t, fc1b, fc2t, fc2b, outg, gateg);
}

// Round 3
// 606.361 us; speedup vs baseline: 1.5698x; 1.4949x over previous
//
#include <hip/hip_runtime.h>
#include <math.h>

// LocalRelationBlock fused kernel for MI355X (gfx950).
// B=8192, C=256, H=W=5, G=8 groups, SE_HID=64.
// R3: 32x32x16 MFMA, 8-way M-split (wave = 1 GN group = 32 ch, N=64 = both samples),
//     barrier-free conv loops with depth-6 A-ring / depth-2 B-ring prefetch,
//     XOR-swizzled Y rows for bank-conflict-free ds_read_b128.

typedef short v8s  __attribute__((ext_vector_type(8)));   // 8 x bf16
typedef short v4s  __attribute__((ext_vector_type(4)));   // 4 x bf16
typedef float v16f __attribute__((ext_vector_type(16)));
typedef float v4f  __attribute__((ext_vector_type(4)));

#define NTHREADS 512
#define NB 2
#define CP 264               // row stride in bf16 elems
#define CPB 528              // row stride bytes (132 dwords -> +4 banks per row)
#define YROWS 49
#define YSB (YROWS*CPB)      // 25872 bytes per sample

// ---- LDS layout (bytes) ----
#define Y_BYTES   (NB*YSB)                    // 51744
#define GB_OFF    (Y_BYTES)                   // g1,b1,g2,b2 : 1024 f32
#define MASK_OFF  (GB_OFF + 1024*4)           // [NB][32] f32
#define POOL_OFF  (MASK_OFF + NB*32*4)        // [NB][256] f32
#define H_OFF     (POOL_OFF + NB*256*4)       // [NB][64] f32
#define GATE_OFF  (H_OFF + NB*64*4)           // [NB][256] f32
#define INVD_OFF  (GATE_OFF + NB*256*4)       // [NB] f32
#define SMEM_BYTES (INVD_OFF + 64)            // 60768

__device__ __forceinline__ unsigned short f2bf(float f){
  unsigned u = __float_as_uint(f);
  u = u + 0x7fffu + ((u >> 16) & 1u);          // RTNE
  return (unsigned short)(u >> 16);
}
// erf via Abramowitz-Stegun 7.1.26 (|eps| < 1.5e-7)
__device__ __forceinline__ float gelu_f(float v){
  float z  = fabsf(v) * 0.70710678118654752f;
  float t  = __builtin_amdgcn_rcpf(fmaf(0.3275911f, z, 1.0f));
  float e  = __builtin_amdgcn_exp2f(-z*z*1.4426950408889634f);
  float p  = fmaf(1.061405429f, t, -1.453152027f);
  p = fmaf(p, t, 1.421413741f);
  p = fmaf(p, t, -0.284496736f);
  p = fmaf(p, t, 0.254829592f);
  float er = fmaf(-p*t, e, 1.0f);
  er = __builtin_copysignf(er, v);
  return 0.5f*v*(1.0f + er);
}

// Pack weights for 32x32x16 MFMA: panels [step][o=256][16] bf16.
// conv1: step s=0..15, k = s*16+kk. conv2: s = tap*16+cb, k-within-tap = cb*16+kk.
__global__ void prep_kernel(const float* __restrict__ W1, const float* __restrict__ W2,
                            const float* __restrict__ fc1w, const float* __restrict__ fc2w,
                            unsigned short* __restrict__ w1p, unsigned short* __restrict__ w2p,
                            float* __restrict__ fc1t, float* __restrict__ fc2t)
{
  int t = blockIdx.x*blockDim.x + threadIdx.x;
  int stride = gridDim.x*blockDim.x;
  for (int i=t; i<16*256*16; i+=stride){
    int s=i>>12, o=(i>>4)&255, kk=i&15;
    w1p[i] = f2bf(W1[o*256 + s*16 + kk]);
  }
  for (int i=t; i<144*256*16; i+=stride){
    int s=i>>12, o=(i>>4)&255, kk=i&15;
    int tap=s>>4, cb=s&15;
    w2p[i] = f2bf(W2[o*2304 + (cb*16+kk)*9 + tap]);
  }
  for (int i=t; i<256*64; i+=stride){ int c=i>>6, h=i&63; fc1t[i]=fc1w[h*256+c]; }
  for (int i=t; i<64*256; i+=stride){ int k=i>>8, c=i&255; fc2t[i]=fc2w[c*64+k]; }
}

__global__ __launch_bounds__(NTHREADS, 4) void lrb_main(
    const float* __restrict__ xg, const float* __restrict__ maskg,
    const float* __restrict__ g1, const float* __restrict__ b1,
    const float* __restrict__ g2, const float* __restrict__ b2,
    const unsigned short* __restrict__ w1p, const unsigned short* __restrict__ w2p,
    const float* __restrict__ fc1t, const float* __restrict__ fc1b,
    const float* __restrict__ fc2t, const float* __restrict__ fc2b,
    float* __restrict__ outg, float* __restrict__ gateg)
{
  extern __shared__ char smem[];
  float* OUTF = (float*)smem;                  // [NB][256][25] f32 reuses Y
  float* GB   = (float*)(smem + GB_OFF);
  float* MS   = (float*)(smem + MASK_OFF);
  float* POOL = (float*)(smem + POOL_OFF);
  float* HS   = (float*)(smem + H_OFF);
  float* GT   = (float*)(smem + GATE_OFF);
  float* INVD = (float*)(smem + INVD_OFF);

  const int tid  = threadIdx.x;
  const int lane = tid & 63;
  const int wid  = tid >> 6;     // 0..7 : M-block (32 ch) == GN group
  const int p    = lane & 31;    // pixel slot (MFMA col / A row)
  const int half = lane >> 5;    // k-half
  const int hx   = half << 4;    // byte offset of k-half within a 32B k-slice
  const bool pv  = (p < 25);
  const int b0   = blockIdx.x * NB;

  // ---------------- phase 1: zero rows 25..48, stage params + mask ----------
  {
    int4 z4; z4.x=z4.y=z4.z=z4.w=0;
    for (int i = tid; i < NB*24*33; i += NTHREADS){
      int nbb = i / 792;
      int rem = i - nbb*792;
      int rr  = 25 + rem/33, cc = rem - (rem/33)*33;
      *(int4*)(smem + nbb*YSB + rr*CPB + cc*16) = z4;
    }
    if (tid < 256){
      GB[tid]=g1[tid]; GB[256+tid]=b1[tid]; GB[512+tid]=g2[tid]; GB[768+tid]=b2[tid];
    }
    if (tid >= 256 && tid < 256 + NB*32){
      int t2 = tid - 256;
      int nbb = t2>>5, pp = t2&31;
      MS[t2] = (pp < 25) ? maskg[(size_t)(b0+nbb)*25 + pp] : 0.f;
    }
  }

  // ---------------- geometry ----------------
  const int pr = p/5, ps = p - 5*(p/5);
  const int pbase = pv ? (7*pr + ps) : 0;     // 7x7 grid base (valid only)
  const int row1  = p;                         // conv1 row (25..31 are zero rows)
  const int kx1   = ((row1>>3)&3)<<4;          // swizzle key
  const size_t aoff = (size_t)((wid*32 + p)*16 + half*8) * 2;  // A-frag byte off in a panel
  const char* w1c = (const char*)w1p;
  const char* w2c = (const char*)w2p;

  v8s A1r[4], B1r[2][2];
  // conv1 A prologue (global; independent of LDS)
  #pragma unroll
  for (int s0=0; s0<4; ++s0) A1r[s0] = *(const v8s*)(w1c + s0*8192 + aoff);

  __syncthreads();   // zeroing complete

  if (tid < NB){
    float s=0.f;
    #pragma unroll
    for (int pp=0;pp<25;++pp) s += MS[tid*32+pp];
    INVD[tid] = __builtin_amdgcn_rcpf(fmaxf(s, 1e-8f));
  }

  // ---------------- phase 2: stage x -> Y rows 0..24 (swizzled) ----------
  for (int i = tid; i < NB*25*32; i += NTHREADS){
    int nbb = i / 800;
    int rem = i - nbb*800;
    int pp  = rem >> 5;        // 0..24
    int c8  = rem & 31;        // channel octet
    const float* src = xg + ((size_t)(b0+nbb)*256 + c8*8)*25 + pp;
    v8s pk;
    #pragma unroll
    for (int k=0;k<8;++k) pk[k] = (short)f2bf(src[k*25]);
    int off = (c8<<4) ^ (((pp>>3)&3)<<4);
    *(v8s*)(smem + nbb*YSB + pp*CPB + off) = pk;
  }
  __syncthreads();

  // ---------------- conv1 (1x1): 16 K-steps of 32x32x16 ----------------
  v16f acc1[2];
  #pragma unroll
  for (int j=0;j<16;++j){ acc1[0][j]=0.f; acc1[1][j]=0.f; }

  #pragma unroll
  for (int s0=0; s0<2; ++s0)
    #pragma unroll
    for (int nt=0; nt<2; ++nt)
      B1r[s0][nt] = *(const v8s*)(smem + nt*YSB + row1*CPB + (((s0<<5)|hx)^kx1));

  #pragma unroll
  for (int s=0; s<16; ++s){
    acc1[0] = __builtin_amdgcn_mfma_f32_32x32x16_bf16(A1r[s&3], B1r[s&1][0], acc1[0], 0,0,0);
    acc1[1] = __builtin_amdgcn_mfma_f32_32x32x16_bf16(A1r[s&3], B1r[s&1][1], acc1[1], 0,0,0);
    if (s+4 < 16) A1r[s&3] = *(const v8s*)(w1c + (s+4)*8192 + aoff);
    if (s+2 < 16){
      #pragma unroll
      for (int nt=0; nt<2; ++nt)
        B1r[s&1][nt] = *(const v8s*)(smem + nt*YSB + row1*CPB + ((((s+2)<<5)|hx)^kx1));
    }
  }

  // ---------------- GN1 (group == wave's 32 ch) + GELU -> y1n grid --------
  {
    float s_[2], q_[2];
    #pragma unroll
    for (int nt=0;nt<2;++nt){
      float a=0.f, b=0.f;
      #pragma unroll
      for (int j=0;j<16;++j){ float v = acc1[nt][j]; a += v; b += v*v; }
      s_[nt]=a; q_[nt]=b;      // invalid columns are exact zeros
    }
    #pragma unroll
    for (int off=1; off<64; off<<=1){
      #pragma unroll
      for (int nt=0;nt<2;++nt){
        s_[nt] += __shfl_xor(s_[nt], off, 64);
        q_[nt] += __shfl_xor(q_[nt], off, 64);
      }
    }
    __syncthreads();   // all conv1 LDS reads complete before grid overwrite

    const int grow = pbase + 8;
    const int kxg  = ((grow>>3)&3)<<4;
    #pragma unroll
    for (int nt=0;nt<2;++nt){
      float mu = s_[nt]*(1.f/800.f);
      float vr = q_[nt]*(1.f/800.f) - mu*mu;
      float rstd = rsqrtf(vr + 1e-5f);
      if (pv){
        #pragma unroll
        for (int q=0;q<4;++q){
          int ch0 = wid*32 + 8*q + 4*half;
          v4s pk;
          #pragma unroll
          for (int i2=0;i2<4;++i2){
            int ch = ch0 + i2;
            float f = (acc1[nt][4*q+i2]-mu)*rstd*GB[ch]+GB[256+ch];
            pk[i2] = (short)f2bf(gelu_f(f));
          }
          *(v4s*)(smem + nt*YSB + grow*CPB + (((wid<<6)+(q<<4)+(half<<3)) ^ kxg)) = pk;
        }
      }
    }
  }
  // re-zero border rows dirtied by staging (rows 0..7,13,14,20,21)
  {
    int4 z4; z4.x=z4.y=z4.z=z4.w=0;
    for (int i = tid; i < NB*12*33; i += NTHREADS){
      int nbb = i / 396;
      int rem = i - nbb*396;
      int rr  = rem/33, cc = rem - (rem/33)*33;
      int row = rr < 8 ? rr : (rr < 10 ? rr + 5 : rr + 10);
      *(int4*)(smem + nbb*YSB + row*CPB + cc*16) = z4;
    }
  }

  // conv2 A prologue (global) before the barrier
  v8s A2r[6], B2r[2][2];
  #pragma unroll
  for (int s0=0; s0<6; ++s0) A2r[s0] = *(const v8s*)(w2c + s0*8192 + aoff);
  __syncthreads();

  // ---------------- conv2: 144 K-steps (9 taps x 16) of 32x32x16 ----------
  v16f acc2[2];
  #pragma unroll
  for (int j=0;j<16;++j){ acc2[0][j]=0.f; acc2[1][j]=0.f; }

  {
    constexpr int OFF7[9] = {0,1,2,7,8,9,14,15,16};
    // B prologue: steps 0,1 (tap 0)
    #pragma unroll
    for (int s0=0; s0<2; ++s0){
      int row2 = pv ? (pbase + OFF7[0]) : (p-24);
      int off  = row2*CPB + (((s0<<5)|hx) ^ (((row2>>3)&3)<<4));
      B2r[s0][0] = *(const v8s*)(smem + off);
      B2r[s0][1] = *(const v8s*)(smem + YSB + off);
    }
    #pragma unroll
    for (int s=0; s<144; ++s){
      acc2[0] = __builtin_amdgcn_mfma_f32_32x32x16_bf16(A2r[s%6], B2r[s&1][0], acc2[0], 0,0,0);
      acc2[1] = __builtin_amdgcn_mfma_f32_32x32x16_bf16(A2r[s%6], B2r[s&1][1], acc2[1], 0,0,0);
      if (s+6 < 144) A2r[s%6] = *(const v8s*)(w2c + (s+6)*8192 + aoff);
      if (s+2 < 144){
        int s2 = s+2;
        int tap = s2>>4, cb = s2&15;
        int row2 = pv ? (pbase + OFF7[tap]) : (p-24);   // rows 1..7 stay zero
        int off  = row2*CPB + (((cb<<5)|hx) ^ (((row2>>3)&3)<<4));
        B2r[s&1][0] = *(const v8s*)(smem + off);
        B2r[s&1][1] = *(const v8s*)(smem + YSB + off);
      }
    }
  }

  // ---------------- GN2 + GELU + residual + OUT-stage + masked pooling ----
  {
    float s_[2], q_[2];
    #pragma unroll
    for (int nt=0;nt<2;++nt){
      float a=0.f, b=0.f;
      #pragma unroll
      for (int j=0;j<16;++j){ float v = acc2[nt][j]; a += v; b += v*v; }
      s_[nt]=a; q_[nt]=b;
    }
    #pragma unroll
    for (int off=1; off<64; off<<=1){
      #pragma unroll
      for (int nt=0;nt<2;++nt){
        s_[nt] += __shfl_xor(s_[nt], off, 64);
        q_[nt] += __shfl_xor(q_[nt], off, 64);
      }
    }
    __syncthreads();   // conv2 LDS reads done; Y becomes OUTF

    float psum[2][16];
    #pragma unroll
    for (int nt=0;nt<2;++nt){
      float mu = s_[nt]*(1.f/800.f);
      float vr = q_[nt]*(1.f/800.f) - mu*mu;
      float rstd = rsqrtf(vr + 1e-5f);
      float mk = pv ? MS[nt*32+p] : 0.f;
      const float* xr = xg + ((size_t)(b0+nt)*256 + wid*32)*25 + p;
      #pragma unroll
      for (int j=0;j<16;++j){
        int crow = (j&3) + 8*(j>>2) + 4*half;
        int ch   = wid*32 + crow;
        float f = (acc2[nt][j]-mu)*rstd*GB[512+ch]+GB[768+ch];
        f = gelu_f(f);
        if (pv){
          f += xr[crow*25];                    // f32 residual
          OUTF[nt*6400 + ch*25 + p] = f;
        }
        psum[nt][j] = f*mk;
      }
    }
    #pragma unroll
    for (int off=1; off<32; off<<=1)
      #pragma unroll
      for (int nt=0;nt<2;++nt)
        #pragma unroll
        for (int j=0;j<16;++j)
          psum[nt][j] += __shfl_xor(psum[nt][j], off, 64);
    if ((lane&31)==0){
      #pragma unroll
      for (int nt=0;nt<2;++nt)
        #pragma unroll
        for (int j=0;j<16;++j)
          POOL[nt*256 + wid*32 + (j&3)+8*(j>>2)+4*half] = psum[nt][j];
    }
  }
  __syncthreads();

  // ---------------- SE FC1: 4-way split dot + shuffle combine --------------
  {
    int nbb  = tid >> 8;          // 0..1
    int hid  = (tid >> 2) & 63;
    int part = tid & 3;
    const float* pl = POOL + nbb*256 + part*64;
    const float* wp = fc1t + part*64*64 + hid;
    float dot = 0.f;
    #pragma unroll 8
    for (int c=0;c<64;++c) dot += wp[c*64]*pl[c];
    dot += __shfl_xor(dot, 1, 64);
    dot += __shfl_xor(dot, 2, 64);
    if (part == 0)
      HS[nbb*64+hid] = gelu_f(fmaf(INVD[nbb], dot, fc1b[hid]));
  }
  __syncthreads();
  // ---------------- SE FC2 -> sigmoid gate (LDS + global) -----------------
  {
    int ch = tid & 255, nbb = tid >> 8;
    const float* hp = HS + nbb*64;
    float dot = 0.f;
    #pragma unroll 8
    for (int k=0;k<64;++k) dot += fc2t[k*256+ch]*hp[k];
    dot += fc2b[ch];
    float gv = __builtin_amdgcn_rcpf(1.0f + __builtin_amdgcn_exp2f(-dot*1.4426950408889634f));
    GT[nbb*256+ch] = gv;
    gateg[(size_t)(b0+nbb)*256+ch] = gv;
  }
  __syncthreads();

  // ---------------- final coalesced store: out = OUTF * gate * mask -------
  for (int i = tid; i < NB*1600; i += NTHREADS){
    int nbb = i / 1600;
    int r4  = i - nbb*1600;
    int e0  = r4*4;
    v4f o4 = *(const v4f*)(OUTF + nbb*6400 + e0);
    #pragma unroll
    for (int k=0;k<4;++k){
      int e = e0+k;
      int ch = e/25;
      int pp = e - ch*25;
      o4[k] = o4[k] * GT[nbb*256+ch] * MS[nbb*32+pp];
    }
    *(v4f*)(outg + (size_t)(b0+nbb)*6400 + e0) = o4;
  }
}

extern "C" void kernel_launch(void* const* d_in, const int* in_sizes, int n_in,
                              void* d_out, int out_size, void* d_ws, size_t ws_size,
                              hipStream_t stream)
{
  const float* xg   = (const float*)d_in[0];
  const float* pm   = (const float*)d_in[1];
  const float* W1   = (const float*)d_in[2];
  const float* g1   = (const float*)d_in[3];
  const float* b1   = (const float*)d_in[4];
  const float* W2   = (const float*)d_in[5];
  const float* g2   = (const float*)d_in[6];
  const float* b2   = (const float*)d_in[7];
  const float* fc1w = (const float*)d_in[8];
  const float* fc1b = (const float*)d_in[9];
  const float* fc2w = (const float*)d_in[10];
  const float* fc2b = (const float*)d_in[11];

  float* outg  = (float*)d_out;
  float* gateg = outg + (size_t)8192*256*25;

  unsigned short* w1p = (unsigned short*)d_ws;        // 16*256*16 bf16
  unsigned short* w2p = w1p + 16*256*16;              // 144*256*16 bf16
  float* fc1t = (float*)(w2p + 144*256*16);           // 256*64 f32 (transposed)
  float* fc2t = fc1t + 256*64;                        // 64*256 f32 (transposed)

  prep_kernel<<<dim3(512), dim3(256), 0, stream>>>(W1, W2, fc1w, fc2w, w1p, w2p, fc1t, fc2t);

  hipFuncSetAttribute(reinterpret_cast<const void*>(lrb_main),
                      hipFuncAttributeMaxDynamicSharedMemorySize, (int)SMEM_BYTES);
  lrb_main<<<dim3(4096), dim3(NTHREADS), SMEM_BYTES, stream>>>(
      xg, pm, g1, b1, g2, b2, w1p, w2p, fc1t, fc1b, fc2t, fc2b, outg, gateg);
}